// Round 3
// baseline (212.332 us; speedup 1.0000x reference)
//
#include <hip/hip_runtime.h>
#include <stdint.h>

// Problem constants
constexpr int NCELLS = 16384 * 49;            // 802816 cells, 30 floats each
constexpr int TCELLS = 128;                   // cells per block tile
constexpr int NTILES = NCELLS / TCELLS;       // 6272 (exact)
constexpr int TILE_BYTES = TCELLS * 120;      // 15360 per tensor (= 15 x 1024)
constexpr int CHUNKS = TILE_BYTES / 1024;     // 15 DMA chunks per tensor

__global__ __launch_bounds__(128) void yolo_stage1(
    const float* __restrict__ pred,
    const float* __restrict__ tgt,
    float* __restrict__ ws)
{
    __shared__ __align__(16) float lds[2 * TCELLS * 30];   // 30720 B -> 5 blocks/CU
    const int tid  = threadIdx.x;
    const int lane = tid & 63;
    const int wv   = tid >> 6;                // 0..1
    const int tile = blockIdx.x;

    // Async global->LDS DMA: wave 0 stages pred tile, wave 1 stages tgt tile.
    // All 15 chunk-loads issued back-to-back, all outstanding (no VGPR
    // round-trip, no per-load waitcnt) -> one latency per tile, not 30.
    {
        const char* g = (wv == 0)
            ? (const char*)pred + (size_t)tile * TILE_BYTES
            : (const char*)tgt  + (size_t)tile * TILE_BYTES;
        char* lbase = (char*)lds + wv * TILE_BYTES;
        #pragma unroll
        for (int j = 0; j < CHUNKS; ++j) {
            __builtin_amdgcn_global_load_lds(
                (const __attribute__((address_space(1))) uint32_t*)(g + j * 1024 + lane * 16),
                (__attribute__((address_space(3))) uint32_t*)(lbase + j * 1024 + lane * 16),
                16, 0, 0);
        }
    }
    asm volatile("s_waitcnt vmcnt(0)" ::: "memory");
    __syncthreads();

    // Each thread computes its own cell from LDS (15 x ds_read_b64).
    const float2* myp = reinterpret_cast<const float2*>(lds) + tid * 15;
    const float2* myt = reinterpret_cast<const float2*>((const char*)lds + TILE_BYTES) + tid * 15;

    float p[30], t[30];
    #pragma unroll
    for (int j = 0; j < 15; ++j) {
        float2 a = myp[j]; p[2*j] = a.x; p[2*j+1] = a.y;
        float2 b = myt[j]; t[2*j] = b.x; t[2*j+1] = b.y;
    }

    const float tconf = t[4];                 // 0.0 or 1.0
    const float m  = (tconf > 0.0f)  ? 1.0f : 0.0f;
    const float nm = (tconf == 0.0f) ? 1.0f : 0.0f;

    // IoU of each pred box vs target box 0 (channels 0..3)
    const float t0x1 = t[0], t0y1 = t[1], t0x2 = t[2], t0y2 = t[3];
    const float a2 = (t0x2 - t0x1) * (t0y2 - t0y1);

    float iou[2];
    #pragma unroll
    for (int b = 0; b < 2; ++b) {
        const float px1 = p[5*b+0], py1 = p[5*b+1];
        const float px2 = p[5*b+2], py2 = p[5*b+3];
        const float ltx = fmaxf(px1, t0x1), lty = fmaxf(py1, t0y1);
        const float rbx = fminf(px2, t0x2), rby = fminf(py2, t0y2);
        const float wx = fmaxf(rbx - ltx, 0.0f), wy = fmaxf(rby - lty, 0.0f);
        const float inter = wx * wy;
        const float a1 = (px2 - px1) * (py2 - py1);
        iou[b] = inter / (a1 + a2 - inter);
    }

    const float max_iou = fmaxf(iou[0], iou[1]);
    const int r = (iou[0] >= iou[1]) ? 0 : 5;   // first index wins ties

    float acc0, acc1, acc2, acc3, acc4;
    {   // xy
        const float dx = p[r+0] - t[r+0];
        const float dy = p[r+1] - t[r+1];
        acc0 = m * (dx*dx + dy*dy);
    }
    {   // wh (sqrt space; inputs in (0.05, 0.95) so sqrt args > 0)
        const float dw = sqrtf(p[r+2]) - sqrtf(t[r+2]);
        const float dh = sqrtf(p[r+3]) - sqrtf(t[r+3]);
        acc1 = m * (dw*dw + dh*dh);
    }
    {   // obj
        const float d = p[r+4] - max_iou;
        acc2 = m * d * d;
    }
    {   // noobj (channels 4, 9)
        const float d0 = p[4] - t[4];
        const float d1 = p[9] - t[9];
        acc3 = nm * (d0*d0 + d1*d1);
    }
    {   // class (channels 10..29)
        float cl = 0.f;
        #pragma unroll
        for (int k = 10; k < 30; ++k) {
            const float d = p[k] - t[k];
            cl += d * d;
        }
        acc4 = m * cl;
    }

    // ---- block reduction: wave shuffle -> LDS -> per-block partials in ws ----
    float acc[5] = {acc0, acc1, acc2, acc3, acc4};
    __shared__ float wave_sums[2][5];
    #pragma unroll
    for (int i = 0; i < 5; ++i) {
        float v = acc[i];
        #pragma unroll
        for (int o = 32; o > 0; o >>= 1)
            v += __shfl_down(v, o, 64);
        if (lane == 0) wave_sums[wv][i] = v;
    }
    __syncthreads();

    // ws layout: [comp][tile] for coalesced stage-2 reads
    if (tid < 5)
        ws[(size_t)tid * NTILES + tile] = wave_sums[0][tid] + wave_sums[1][tid];
}

__global__ __launch_bounds__(256) void yolo_stage2(
    const float* __restrict__ ws, float* __restrict__ out)
{
    const int c = blockIdx.x;                  // 0..4
    const float* src = ws + (size_t)c * NTILES;
    float v = 0.f;
    for (int i = threadIdx.x; i < NTILES; i += 256) v += src[i];

    __shared__ float wsum[4];
    #pragma unroll
    for (int o = 32; o > 0; o >>= 1) v += __shfl_down(v, o, 64);
    if ((threadIdx.x & 63) == 0) wsum[threadIdx.x >> 6] = v;
    __syncthreads();
    if (threadIdx.x == 0) out[c] = wsum[0] + wsum[1] + wsum[2] + wsum[3];
}

extern "C" void kernel_launch(void* const* d_in, const int* in_sizes, int n_in,
                              void* d_out, int out_size, void* d_ws, size_t ws_size,
                              hipStream_t stream) {
    const float* pred = (const float*)d_in[0];
    const float* tgt  = (const float*)d_in[1];
    float* out = (float*)d_out;
    float* ws  = (float*)d_ws;                 // needs 5*6272*4 = 125440 B

    hipLaunchKernelGGL(yolo_stage1, dim3(NTILES), dim3(128), 0, stream, pred, tgt, ws);
    hipLaunchKernelGGL(yolo_stage2, dim3(5), dim3(256), 0, stream, ws, out);
}